// Round 1
// baseline (1031.386 us; speedup 1.0000x reference)
//
#include <hip/hip_runtime.h>
#include <cstdint>
#include <cstddef>

static constexpr int N_NODES = 100000;
static constexpr int N_GRAPHS = 256;
static constexpr int HF = 64;

#define SCAN_T 256
#define SCAN_E 8
#define SCAN_CHUNK (SCAN_T * SCAN_E)

// ---------- degree histogram over dst ----------
__global__ void hist_k(const int* __restrict__ dst, int* __restrict__ deg, int E) {
    int e = blockIdx.x * blockDim.x + threadIdx.x;
    if (e < E) atomicAdd(&deg[dst[e]], 1);
}

// ---------- dinv = rsqrt(indeg + 1)  (self loop) ----------
__global__ void dinv_k(const int* __restrict__ deg, float* __restrict__ dinv, int n) {
    int v = blockIdx.x * blockDim.x + threadIdx.x;
    if (v < n) dinv[v] = rsqrtf((float)(deg[v] + 1));
}

// ---------- exclusive scan (3-pass) ----------
__global__ void scan1_k(const int* __restrict__ in, int* __restrict__ out,
                        int* __restrict__ sums, int n) {
    __shared__ int lds[SCAN_T];
    int t = threadIdx.x;
    int base = blockIdx.x * SCAN_CHUNK + t * SCAN_E;
    int v[SCAN_E];
    int s = 0;
#pragma unroll
    for (int i = 0; i < SCAN_E; ++i) {
        int idx = base + i;
        int x = (idx < n) ? in[idx] : 0;
        v[i] = s; s += x;
    }
    lds[t] = s; __syncthreads();
    for (int off = 1; off < SCAN_T; off <<= 1) {
        int a = (t >= off) ? lds[t - off] : 0;
        __syncthreads();
        lds[t] += a;
        __syncthreads();
    }
    int excl = (t == 0) ? 0 : lds[t - 1];
    if (t == SCAN_T - 1) sums[blockIdx.x] = lds[SCAN_T - 1];
#pragma unroll
    for (int i = 0; i < SCAN_E; ++i) {
        int idx = base + i;
        if (idx < n) out[idx] = excl + v[i];
    }
}

__global__ void scan2_k(int* __restrict__ sums, int nb) {
    __shared__ int lds[SCAN_T];
    int t = threadIdx.x;
    lds[t] = (t < nb) ? sums[t] : 0;
    __syncthreads();
    for (int off = 1; off < SCAN_T; off <<= 1) {
        int a = (t >= off) ? lds[t - off] : 0;
        __syncthreads();
        lds[t] += a;
        __syncthreads();
    }
    int excl = (t == 0) ? 0 : lds[t - 1];
    if (t < nb) sums[t] = excl;
}

__global__ void scan3_k(int* __restrict__ out, const int* __restrict__ sums, int n) {
    int idx = blockIdx.x * blockDim.x + threadIdx.x;
    if (idx < n) out[idx] += sums[idx / SCAN_CHUNK];
}

// ---------- CSR fill (by dst) ----------
__global__ void fill_k(const int* __restrict__ src, const int* __restrict__ dst,
                       const int* __restrict__ row_ptr, int* __restrict__ pos,
                       int* __restrict__ col, int E) {
    int e = blockIdx.x * blockDim.x + threadIdx.x;
    if (e < E) {
        int d = dst[e];
        int p = atomicAdd(&pos[d], 1);
        col[row_ptr[d] + p] = src[e];
    }
}

// ---------- u = (in @ W) * dinv[row]   (W staged in LDS) ----------
template <int K>
__global__ void gemm_scale_k(const float* __restrict__ in, const float* __restrict__ W,
                             const float* __restrict__ dinv, float* __restrict__ u, int n) {
    __shared__ float Wl[K * HF];
    for (int i = threadIdx.x; i < K * HF; i += blockDim.x) Wl[i] = W[i];
    __syncthreads();
    int wave = threadIdx.x >> 6, lane = threadIdx.x & 63;
    int row = blockIdx.x * 4 + wave;
    if (row >= n) return;
    const float* xr = in + (size_t)row * K;
    float acc = 0.f;
#pragma unroll
    for (int k4 = 0; k4 < K / 4; ++k4) {
        float4 xv = *(const float4*)(xr + k4 * 4);
        acc += xv.x * Wl[(4 * k4 + 0) * HF + lane];
        acc += xv.y * Wl[(4 * k4 + 1) * HF + lane];
        acc += xv.z * Wl[(4 * k4 + 2) * HF + lane];
        acc += xv.w * Wl[(4 * k4 + 3) * HF + lane];
    }
    u[(size_t)row * HF + lane] = acc * dinv[row];
}

// ---------- aggregation: out[v] = relu(dinv[v]*(sum_in u[s] + u[v]) + b) ----------
__global__ void agg_k(const float* __restrict__ u, const int* __restrict__ col,
                      const int* __restrict__ row_ptr, const int* __restrict__ deg,
                      const float* __restrict__ dinv, const float* __restrict__ bias,
                      float* __restrict__ out, int n) {
    int wave = threadIdx.x >> 6, lane = threadIdx.x & 63;
    int v = blockIdx.x * 4 + wave;
    if (v >= n) return;
    int start = row_ptr[v];
    int end = start + deg[v];
    float acc = u[(size_t)v * HF + lane];  // self loop
    for (int e = start; e < end;) {
        int m = min(64, end - e);
        int c = (lane < m) ? col[e + lane] : 0;
        int t = 0;
        for (; t + 4 <= m; t += 4) {
            int s0 = __shfl(c, t), s1 = __shfl(c, t + 1);
            int s2 = __shfl(c, t + 2), s3 = __shfl(c, t + 3);
            float a0 = u[(size_t)s0 * HF + lane];
            float a1 = u[(size_t)s1 * HF + lane];
            float a2 = u[(size_t)s2 * HF + lane];
            float a3 = u[(size_t)s3 * HF + lane];
            acc += a0; acc += a1; acc += a2; acc += a3;
        }
        for (; t < m; ++t) {
            int s = __shfl(c, t);
            acc += u[(size_t)s * HF + lane];
        }
        e += m;
    }
    out[(size_t)v * HF + lane] = fmaxf(fmaf(acc, dinv[v], bias[lane]), 0.f);
}

// ---------- fused mean-pool + linear head ----------
__device__ __forceinline__ int lower_bound_i(const int* a, int n, int key) {
    int lo = 0, hi = n;
    while (lo < hi) { int mid = (lo + hi) >> 1; if (a[mid] < key) lo = mid + 1; else hi = mid; }
    return lo;
}

__global__ void pool_head_k(const float* __restrict__ h, const int* __restrict__ batch,
                            const float* __restrict__ Wl, const float* __restrict__ bl,
                            float* __restrict__ out, int n) {
    __shared__ float ssum[4][HF];
    __shared__ float smean[HF];
    int g = blockIdx.x;
    int wave = threadIdx.x >> 6, lane = threadIdx.x & 63;
    int start = lower_bound_i(batch, n, g);
    int end = lower_bound_i(batch, n, g + 1);
    float acc = 0.f;
    for (int v = start + wave; v < end; v += 4) acc += h[(size_t)v * HF + lane];
    ssum[wave][lane] = acc;
    __syncthreads();
    if (wave == 0) {
        float s = ssum[0][lane] + ssum[1][lane] + ssum[2][lane] + ssum[3][lane];
        float cnt = (float)(end - start);
        smean[lane] = s / fmaxf(cnt, 1.f);
    }
    __syncthreads();
    if (threadIdx.x < 2) {
        float o = bl[threadIdx.x];
        for (int j = 0; j < HF; ++j) o += smean[j] * Wl[j * 2 + threadIdx.x];
        out[g * 2 + threadIdx.x] = o;
    }
}

extern "C" void kernel_launch(void* const* d_in, const int* in_sizes, int n_in,
                              void* d_out, int out_size, void* d_ws, size_t ws_size,
                              hipStream_t stream) {
    const float* x     = (const float*)d_in[0];
    const int*   ei    = (const int*)d_in[1];
    const int*   batch = (const int*)d_in[2];
    const float* W1 = (const float*)d_in[3];
    const float* b1 = (const float*)d_in[4];
    const float* W2 = (const float*)d_in[5];
    const float* b2 = (const float*)d_in[6];
    const float* W3 = (const float*)d_in[7];
    const float* b3 = (const float*)d_in[8];
    const float* Wl = (const float*)d_in[9];
    const float* bl = (const float*)d_in[10];
    float* outp = (float*)d_out;

    const int N = N_NODES;
    const int E = in_sizes[1] / 2;

    char* ws = (char*)d_ws;
    size_t off = 0;
    auto alloc = [&](size_t bytes) {
        void* p = ws + off;
        off = (off + bytes + 255) & ~size_t(255);
        return p;
    };
    float* P    = (float*)alloc((size_t)N * HF * 4);
    float* U    = (float*)alloc((size_t)N * HF * 4);
    int*   colA = (int*)alloc((size_t)E * 4);
    int*   deg  = (int*)alloc((size_t)N * 4);
    float* dinv = (float*)alloc((size_t)N * 4);
    int*   rowp = (int*)alloc((size_t)N * 4);
    int*   posA = (int*)alloc((size_t)N * 4);
    int*   sums = (int*)alloc(1024);
    (void)ws_size; (void)n_in; (void)out_size;

    const int* src = ei;
    const int* dst = ei + E;

    hipMemsetAsync(deg, 0, (size_t)N * 4, stream);
    hipMemsetAsync(posA, 0, (size_t)N * 4, stream);

    int gE = (E + 255) / 256;
    int gN = (N + 255) / 256;
    hist_k<<<gE, 256, 0, stream>>>(dst, deg, E);
    dinv_k<<<gN, 256, 0, stream>>>(deg, dinv, N);
    int nb = (N + SCAN_CHUNK - 1) / SCAN_CHUNK;
    scan1_k<<<nb, SCAN_T, 0, stream>>>(deg, rowp, sums, N);
    scan2_k<<<1, SCAN_T, 0, stream>>>(sums, nb);
    scan3_k<<<gN, 256, 0, stream>>>(rowp, sums, N);
    fill_k<<<gE, 256, 0, stream>>>(src, dst, rowp, posA, colA, E);

    int gRow = (N + 3) / 4;
    // layer 1 (K=128)
    gemm_scale_k<128><<<gRow, 256, 0, stream>>>(x, W1, dinv, U, N);
    agg_k<<<gRow, 256, 0, stream>>>(U, colA, rowp, deg, dinv, b1, P, N);
    // layer 2 (K=64)
    gemm_scale_k<64><<<gRow, 256, 0, stream>>>(P, W2, dinv, U, N);
    agg_k<<<gRow, 256, 0, stream>>>(U, colA, rowp, deg, dinv, b2, P, N);
    // layer 3 (K=64)
    gemm_scale_k<64><<<gRow, 256, 0, stream>>>(P, W3, dinv, U, N);
    agg_k<<<gRow, 256, 0, stream>>>(U, colA, rowp, deg, dinv, b3, P, N);

    pool_head_k<<<N_GRAPHS, 256, 0, stream>>>(P, batch, Wl, bl, outp, N);
}

// Round 2
// 939.062 us; speedup vs baseline: 1.0983x; 1.0983x over previous
//
#include <hip/hip_runtime.h>
#include <cstdint>
#include <cstddef>

static constexpr int N_NODES = 100000;
static constexpr int N_GRAPHS = 256;
static constexpr int HF = 64;

#define SCAN_T 256
#define SCAN_E 8
#define SCAN_CHUNK (SCAN_T * SCAN_E)

// ---------- degree histogram over dst ----------
__global__ void hist_k(const int* __restrict__ dst, int* __restrict__ deg, int E) {
    int e = blockIdx.x * blockDim.x + threadIdx.x;
    if (e < E) atomicAdd(&deg[dst[e]], 1);
}

// ---------- dinv = rsqrt(indeg + 1)  (self loop) ----------
__global__ void dinv_k(const int* __restrict__ deg, float* __restrict__ dinv, int n) {
    int v = blockIdx.x * blockDim.x + threadIdx.x;
    if (v < n) dinv[v] = rsqrtf((float)(deg[v] + 1));
}

// ---------- exclusive scan (3-pass) ----------
__global__ void scan1_k(const int* __restrict__ in, int* __restrict__ out,
                        int* __restrict__ sums, int n) {
    __shared__ int lds[SCAN_T];
    int t = threadIdx.x;
    int base = blockIdx.x * SCAN_CHUNK + t * SCAN_E;
    int v[SCAN_E];
    int s = 0;
#pragma unroll
    for (int i = 0; i < SCAN_E; ++i) {
        int idx = base + i;
        int x = (idx < n) ? in[idx] : 0;
        v[i] = s; s += x;
    }
    lds[t] = s; __syncthreads();
    for (int off = 1; off < SCAN_T; off <<= 1) {
        int a = (t >= off) ? lds[t - off] : 0;
        __syncthreads();
        lds[t] += a;
        __syncthreads();
    }
    int excl = (t == 0) ? 0 : lds[t - 1];
    if (t == SCAN_T - 1) sums[blockIdx.x] = lds[SCAN_T - 1];
#pragma unroll
    for (int i = 0; i < SCAN_E; ++i) {
        int idx = base + i;
        if (idx < n) out[idx] = excl + v[i];
    }
}

__global__ void scan2_k(int* __restrict__ sums, int nb) {
    __shared__ int lds[SCAN_T];
    int t = threadIdx.x;
    lds[t] = (t < nb) ? sums[t] : 0;
    __syncthreads();
    for (int off = 1; off < SCAN_T; off <<= 1) {
        int a = (t >= off) ? lds[t - off] : 0;
        __syncthreads();
        lds[t] += a;
        __syncthreads();
    }
    int excl = (t == 0) ? 0 : lds[t - 1];
    if (t < nb) sums[t] = excl;
}

__global__ void scan3_k(int* __restrict__ out, const int* __restrict__ sums, int n) {
    int idx = blockIdx.x * blockDim.x + threadIdx.x;
    if (idx < n) out[idx] += sums[idx / SCAN_CHUNK];
}

// ---------- CSR fill (by dst) ----------
__global__ void fill_k(const int* __restrict__ src, const int* __restrict__ dst,
                       const int* __restrict__ row_ptr, int* __restrict__ pos,
                       int* __restrict__ col, int E) {
    int e = blockIdx.x * blockDim.x + threadIdx.x;
    if (e < E) {
        int d = dst[e];
        int p = atomicAdd(&pos[d], 1);
        col[row_ptr[d] + p] = src[e];
    }
}

// ---------- W transpose: W4[k4*64+c] = {W[4k4..4k4+3][c]} ----------
__global__ void wtrans_k(const float* __restrict__ W, float4* __restrict__ W4, int total) {
    int idx = blockIdx.x * blockDim.x + threadIdx.x;
    if (idx >= total) return;
    int k4 = idx >> 6, c = idx & 63;
    W4[idx] = make_float4(W[(4 * k4 + 0) * HF + c], W[(4 * k4 + 1) * HF + c],
                          W[(4 * k4 + 2) * HF + c], W[(4 * k4 + 3) * HF + c]);
}

// ---------- u = (in @ W) * dinv[row]   (register-tiled, W4 in LDS) ----------
// Block = 256 threads (4 waves), 64 rows per block (16/wave), lane = out col.
template <int K>
__global__ __launch_bounds__(256) void gemm2_k(const float* __restrict__ in,
                                               const float4* __restrict__ W4,
                                               const float* __restrict__ dinv,
                                               float* __restrict__ u, int n) {
    __shared__ float4 Wl[(K / 4) * HF];
    for (int i = threadIdx.x; i < (K / 4) * HF; i += 256) Wl[i] = W4[i];
    __syncthreads();
    int wave = threadIdx.x >> 6, lane = threadIdx.x & 63;
    int rb = blockIdx.x * 64 + wave * 16;
#pragma unroll
    for (int g = 0; g < 4; ++g) {
        int r0 = rb + g * 4;
        if (r0 >= n) return;
        if (r0 + 4 <= n) {
            const float4* x0 = (const float4*)(in + (size_t)(r0 + 0) * K);
            const float4* x1 = (const float4*)(in + (size_t)(r0 + 1) * K);
            const float4* x2 = (const float4*)(in + (size_t)(r0 + 2) * K);
            const float4* x3 = (const float4*)(in + (size_t)(r0 + 3) * K);
            float a0 = 0.f, a1 = 0.f, a2 = 0.f, a3 = 0.f;
#pragma unroll 4
            for (int k4 = 0; k4 < K / 4; ++k4) {
                float4 w = Wl[k4 * HF + lane];
                float4 v0 = x0[k4], v1 = x1[k4], v2 = x2[k4], v3 = x3[k4];
                a0 = fmaf(v0.x, w.x, fmaf(v0.y, w.y, fmaf(v0.z, w.z, fmaf(v0.w, w.w, a0))));
                a1 = fmaf(v1.x, w.x, fmaf(v1.y, w.y, fmaf(v1.z, w.z, fmaf(v1.w, w.w, a1))));
                a2 = fmaf(v2.x, w.x, fmaf(v2.y, w.y, fmaf(v2.z, w.z, fmaf(v2.w, w.w, a2))));
                a3 = fmaf(v3.x, w.x, fmaf(v3.y, w.y, fmaf(v3.z, w.z, fmaf(v3.w, w.w, a3))));
            }
            u[(size_t)(r0 + 0) * HF + lane] = a0 * dinv[r0 + 0];
            u[(size_t)(r0 + 1) * HF + lane] = a1 * dinv[r0 + 1];
            u[(size_t)(r0 + 2) * HF + lane] = a2 * dinv[r0 + 2];
            u[(size_t)(r0 + 3) * HF + lane] = a3 * dinv[r0 + 3];
        } else {
            for (int i = 0; i < 4; ++i) {
                int r = r0 + i;
                if (r >= n) break;
                const float4* xr = (const float4*)(in + (size_t)r * K);
                float a = 0.f;
                for (int k4 = 0; k4 < K / 4; ++k4) {
                    float4 w = Wl[k4 * HF + lane];
                    float4 v = xr[k4];
                    a = fmaf(v.x, w.x, fmaf(v.y, w.y, fmaf(v.z, w.z, fmaf(v.w, w.w, a))));
                }
                u[(size_t)r * HF + lane] = a * dinv[r];
            }
        }
    }
}

// ---------- aggregation: out[v] = relu(dinv[v]*(sum_in u[s] + u[v]) + b) ----------
__global__ void agg_k(const float* __restrict__ u, const int* __restrict__ col,
                      const int* __restrict__ row_ptr, const int* __restrict__ deg,
                      const float* __restrict__ dinv, const float* __restrict__ bias,
                      float* __restrict__ out, int n) {
    int wave = threadIdx.x >> 6, lane = threadIdx.x & 63;
    int v = blockIdx.x * 4 + wave;
    if (v >= n) return;
    int start = row_ptr[v];
    int end = start + deg[v];
    float acc = u[(size_t)v * HF + lane];  // self loop
    for (int e = start; e < end;) {
        int m = min(64, end - e);
        int c = (lane < m) ? col[e + lane] : 0;
        int t = 0;
        for (; t + 4 <= m; t += 4) {
            int s0 = __shfl(c, t), s1 = __shfl(c, t + 1);
            int s2 = __shfl(c, t + 2), s3 = __shfl(c, t + 3);
            float a0 = u[(size_t)s0 * HF + lane];
            float a1 = u[(size_t)s1 * HF + lane];
            float a2 = u[(size_t)s2 * HF + lane];
            float a3 = u[(size_t)s3 * HF + lane];
            acc += a0; acc += a1; acc += a2; acc += a3;
        }
        for (; t < m; ++t) {
            int s = __shfl(c, t);
            acc += u[(size_t)s * HF + lane];
        }
        e += m;
    }
    out[(size_t)v * HF + lane] = fmaxf(fmaf(acc, dinv[v], bias[lane]), 0.f);
}

// ---------- fused mean-pool + linear head ----------
__device__ __forceinline__ int lower_bound_i(const int* a, int n, int key) {
    int lo = 0, hi = n;
    while (lo < hi) { int mid = (lo + hi) >> 1; if (a[mid] < key) lo = mid + 1; else hi = mid; }
    return lo;
}

__global__ void pool_head_k(const float* __restrict__ h, const int* __restrict__ batch,
                            const float* __restrict__ Wl, const float* __restrict__ bl,
                            float* __restrict__ out, int n) {
    __shared__ float ssum[4][HF];
    __shared__ float smean[HF];
    int g = blockIdx.x;
    int wave = threadIdx.x >> 6, lane = threadIdx.x & 63;
    int start = lower_bound_i(batch, n, g);
    int end = lower_bound_i(batch, n, g + 1);
    float acc = 0.f;
    for (int v = start + wave; v < end; v += 4) acc += h[(size_t)v * HF + lane];
    ssum[wave][lane] = acc;
    __syncthreads();
    if (wave == 0) {
        float s = ssum[0][lane] + ssum[1][lane] + ssum[2][lane] + ssum[3][lane];
        float cnt = (float)(end - start);
        smean[lane] = s / fmaxf(cnt, 1.f);
    }
    __syncthreads();
    if (threadIdx.x < 2) {
        float o = bl[threadIdx.x];
        for (int j = 0; j < HF; ++j) o += smean[j] * Wl[j * 2 + threadIdx.x];
        out[g * 2 + threadIdx.x] = o;
    }
}

extern "C" void kernel_launch(void* const* d_in, const int* in_sizes, int n_in,
                              void* d_out, int out_size, void* d_ws, size_t ws_size,
                              hipStream_t stream) {
    const float* x     = (const float*)d_in[0];
    const int*   ei    = (const int*)d_in[1];
    const int*   batch = (const int*)d_in[2];
    const float* W1 = (const float*)d_in[3];
    const float* b1 = (const float*)d_in[4];
    const float* W2 = (const float*)d_in[5];
    const float* b2 = (const float*)d_in[6];
    const float* W3 = (const float*)d_in[7];
    const float* b3 = (const float*)d_in[8];
    const float* Wl = (const float*)d_in[9];
    const float* bl = (const float*)d_in[10];
    float* outp = (float*)d_out;

    const int N = N_NODES;
    const int E = in_sizes[1] / 2;

    char* ws = (char*)d_ws;
    size_t off = 0;
    auto alloc = [&](size_t bytes) {
        void* p = ws + off;
        off = (off + bytes + 255) & ~size_t(255);
        return p;
    };
    float*  P    = (float*)alloc((size_t)N * HF * 4);
    float*  U    = (float*)alloc((size_t)N * HF * 4);
    int*    colA = (int*)alloc((size_t)E * 4);
    int*    deg  = (int*)alloc((size_t)N * 4);
    float*  dinv = (float*)alloc((size_t)N * 4);
    int*    rowp = (int*)alloc((size_t)N * 4);
    int*    posA = (int*)alloc((size_t)N * 4);
    int*    sums = (int*)alloc(1024);
    float4* W4_1 = (float4*)alloc((size_t)(128 / 4) * HF * 16);
    float4* W4_2 = (float4*)alloc((size_t)(64 / 4) * HF * 16);
    float4* W4_3 = (float4*)alloc((size_t)(64 / 4) * HF * 16);
    (void)ws_size; (void)n_in; (void)out_size;

    const int* src = ei;
    const int* dst = ei + E;

    hipMemsetAsync(deg, 0, (size_t)N * 4, stream);
    hipMemsetAsync(posA, 0, (size_t)N * 4, stream);

    int gE = (E + 255) / 256;
    int gN = (N + 255) / 256;
    hist_k<<<gE, 256, 0, stream>>>(dst, deg, E);
    dinv_k<<<gN, 256, 0, stream>>>(deg, dinv, N);
    int nb = (N + SCAN_CHUNK - 1) / SCAN_CHUNK;
    scan1_k<<<nb, SCAN_T, 0, stream>>>(deg, rowp, sums, N);
    scan2_k<<<1, SCAN_T, 0, stream>>>(sums, nb);
    scan3_k<<<gN, 256, 0, stream>>>(rowp, sums, N);
    fill_k<<<gE, 256, 0, stream>>>(src, dst, rowp, posA, colA, E);

    // one-time W transforms (cheap)
    wtrans_k<<<(32 * HF + 255) / 256, 256, 0, stream>>>(W1, W4_1, 32 * HF);
    wtrans_k<<<(16 * HF + 255) / 256, 256, 0, stream>>>(W2, W4_2, 16 * HF);
    wtrans_k<<<(16 * HF + 255) / 256, 256, 0, stream>>>(W3, W4_3, 16 * HF);

    int gRow = (N + 3) / 4;       // agg: 4 nodes/block
    int gRow64 = (N + 63) / 64;   // gemm: 64 rows/block
    // layer 1 (K=128)
    gemm2_k<128><<<gRow64, 256, 0, stream>>>(x, W4_1, dinv, U, N);
    agg_k<<<gRow, 256, 0, stream>>>(U, colA, rowp, deg, dinv, b1, P, N);
    // layer 2 (K=64)
    gemm2_k<64><<<gRow64, 256, 0, stream>>>(P, W4_2, dinv, U, N);
    agg_k<<<gRow, 256, 0, stream>>>(U, colA, rowp, deg, dinv, b2, P, N);
    // layer 3 (K=64)
    gemm2_k<64><<<gRow64, 256, 0, stream>>>(P, W4_3, dinv, U, N);
    agg_k<<<gRow, 256, 0, stream>>>(U, colA, rowp, deg, dinv, b3, P, N);

    pool_head_k<<<N_GRAPHS, 256, 0, stream>>>(P, batch, Wl, bl, outp, N);
}

// Round 3
// 703.430 us; speedup vs baseline: 1.4662x; 1.3350x over previous
//
#include <hip/hip_runtime.h>
#include <cstdint>
#include <cstddef>

static constexpr int N_NODES = 100000;
static constexpr int N_GRAPHS = 256;
static constexpr int HF = 64;

#define SCAN_T 256
#define SCAN_E 8
#define SCAN_CHUNK (SCAN_T * SCAN_E)

#define BSHIFT 9
#define BNODES 512
#define ECHUNK 16384

// ---------- exclusive scan (3-pass) ----------
__global__ void scan1_k(const int* __restrict__ in, int* __restrict__ out,
                        int* __restrict__ sums, int n) {
    __shared__ int lds[SCAN_T];
    int t = threadIdx.x;
    int base = blockIdx.x * SCAN_CHUNK + t * SCAN_E;
    int v[SCAN_E];
    int s = 0;
#pragma unroll
    for (int i = 0; i < SCAN_E; ++i) {
        int idx = base + i;
        int x = (idx < n) ? in[idx] : 0;
        v[i] = s; s += x;
    }
    lds[t] = s; __syncthreads();
    for (int off = 1; off < SCAN_T; off <<= 1) {
        int a = (t >= off) ? lds[t - off] : 0;
        __syncthreads();
        lds[t] += a;
        __syncthreads();
    }
    int excl = (t == 0) ? 0 : lds[t - 1];
    if (t == SCAN_T - 1) sums[blockIdx.x] = lds[SCAN_T - 1];
#pragma unroll
    for (int i = 0; i < SCAN_E; ++i) {
        int idx = base + i;
        if (idx < n) out[idx] = excl + v[i];
    }
}

__global__ void scan2_k(int* __restrict__ sums, int nb) {
    __shared__ int lds[SCAN_T];
    int t = threadIdx.x;
    lds[t] = (t < nb) ? sums[t] : 0;
    __syncthreads();
    for (int off = 1; off < SCAN_T; off <<= 1) {
        int a = (t >= off) ? lds[t - off] : 0;
        __syncthreads();
        lds[t] += a;
        __syncthreads();
    }
    int excl = (t == 0) ? 0 : lds[t - 1];
    if (t < nb) sums[t] = excl;
}

__global__ void scan3_k(int* __restrict__ out, const int* __restrict__ sums, int n) {
    int idx = blockIdx.x * blockDim.x + threadIdx.x;
    if (idx < n) out[idx] += sums[idx / SCAN_CHUNK];
}

// ---------- per-chunk bucket histogram ----------
__global__ void bhist_k(const int* __restrict__ dst, int* __restrict__ cnt,
                        int E, int nblk, int NB) {
    __shared__ int c[256];
    int t = threadIdx.x;
    c[t] = 0;
    __syncthreads();
    int base = blockIdx.x * ECHUNK;
    for (int i = t; i < ECHUNK; i += 256) {
        int e = base + i;
        if (e >= E) break;
        atomicAdd(&c[dst[e] >> BSHIFT], 1);
    }
    __syncthreads();
    if (t < NB) cnt[t * nblk + blockIdx.x] = c[t];
}

// ---------- scatter edges into bucket partitions ----------
__global__ void scatter_k(const int* __restrict__ src, const int* __restrict__ dst,
                          const int* __restrict__ scn, int2* __restrict__ es,
                          int E, int nblk, int NB) {
    __shared__ int offs[256];
    int t = threadIdx.x;
    if (t < NB) offs[t] = scn[t * nblk + blockIdx.x];
    __syncthreads();
    int base = blockIdx.x * ECHUNK;
    for (int i = t; i < ECHUNK; i += 256) {
        int e = base + i;
        if (e >= E) break;
        int d = dst[e];
        int b = d >> BSHIFT;
        int p = atomicAdd(&offs[b], 1);
        es[p] = make_int2(src[e], d);
    }
}

// ---------- per-bucket: local deg, row_ptr, dinv, CSR col fill ----------
__global__ void fill2_k(const int2* __restrict__ es, const int* __restrict__ scn,
                        int* __restrict__ rowp, int* __restrict__ deg,
                        float* __restrict__ dinv, int* __restrict__ col,
                        int E, int nblk, int NB, int N) {
    __shared__ int ldeg[BNODES];
    __shared__ int rp[BNODES];
    __shared__ int ps[256];
    int b = blockIdx.x, t = threadIdx.x;
    int ebase = scn[b * nblk];
    int eend = (b + 1 < NB) ? scn[(b + 1) * nblk] : E;
    int d0 = b << BSHIFT;
    int nd = min(BNODES, N - d0);
    ldeg[t] = 0; ldeg[t + 256] = 0;
    __syncthreads();
    for (int e = ebase + t; e < eend; e += 256) atomicAdd(&ldeg[es[e].y - d0], 1);
    __syncthreads();
    // exclusive scan of ldeg[0..511] -> rp
    int a0 = ldeg[2 * t], a1 = ldeg[2 * t + 1];
    ps[t] = a0 + a1;
    __syncthreads();
    for (int off = 1; off < 256; off <<= 1) {
        int v = (t >= off) ? ps[t - off] : 0;
        __syncthreads();
        ps[t] += v;
        __syncthreads();
    }
    int ex = (t == 0) ? 0 : ps[t - 1];
    rp[2 * t] = ex;
    rp[2 * t + 1] = ex + a0;
    __syncthreads();
    for (int i = t; i < nd; i += 256) {
        int d = d0 + i;
        rowp[d] = ebase + rp[i];
        int dg = ldeg[i];
        deg[d] = dg;
        dinv[d] = rsqrtf((float)(dg + 1));
    }
    __syncthreads();
    ldeg[t] = 0; ldeg[t + 256] = 0;  // reuse as position counters
    __syncthreads();
    for (int e = ebase + t; e < eend; e += 256) {
        int2 ed = es[e];
        int li = ed.y - d0;
        int p = atomicAdd(&ldeg[li], 1);
        col[ebase + rp[li] + p] = ed.x;
    }
}

// ---------- W transpose: W4[k4*64+c] = {W[4k4..4k4+3][c]} ----------
__global__ void wtrans_k(const float* __restrict__ W, float4* __restrict__ W4, int total) {
    int idx = blockIdx.x * blockDim.x + threadIdx.x;
    if (idx >= total) return;
    int k4 = idx >> 6, c = idx & 63;
    W4[idx] = make_float4(W[(4 * k4 + 0) * HF + c], W[(4 * k4 + 1) * HF + c],
                          W[(4 * k4 + 2) * HF + c], W[(4 * k4 + 3) * HF + c]);
}

// ---------- u = (in @ W) * dinv[row]   (register-tiled, W4 in LDS) ----------
template <int K>
__global__ __launch_bounds__(256) void gemm2_k(const float* __restrict__ in,
                                               const float4* __restrict__ W4,
                                               const float* __restrict__ dinv,
                                               float* __restrict__ u, int n) {
    __shared__ float4 Wl[(K / 4) * HF];
    for (int i = threadIdx.x; i < (K / 4) * HF; i += 256) Wl[i] = W4[i];
    __syncthreads();
    int wave = threadIdx.x >> 6, lane = threadIdx.x & 63;
    int rb = blockIdx.x * 64 + wave * 16;
#pragma unroll
    for (int g = 0; g < 4; ++g) {
        int r0 = rb + g * 4;
        if (r0 >= n) return;
        if (r0 + 4 <= n) {
            const float4* x0 = (const float4*)(in + (size_t)(r0 + 0) * K);
            const float4* x1 = (const float4*)(in + (size_t)(r0 + 1) * K);
            const float4* x2 = (const float4*)(in + (size_t)(r0 + 2) * K);
            const float4* x3 = (const float4*)(in + (size_t)(r0 + 3) * K);
            float a0 = 0.f, a1 = 0.f, a2 = 0.f, a3 = 0.f;
#pragma unroll 4
            for (int k4 = 0; k4 < K / 4; ++k4) {
                float4 w = Wl[k4 * HF + lane];
                float4 v0 = x0[k4], v1 = x1[k4], v2 = x2[k4], v3 = x3[k4];
                a0 = fmaf(v0.x, w.x, fmaf(v0.y, w.y, fmaf(v0.z, w.z, fmaf(v0.w, w.w, a0))));
                a1 = fmaf(v1.x, w.x, fmaf(v1.y, w.y, fmaf(v1.z, w.z, fmaf(v1.w, w.w, a1))));
                a2 = fmaf(v2.x, w.x, fmaf(v2.y, w.y, fmaf(v2.z, w.z, fmaf(v2.w, w.w, a2))));
                a3 = fmaf(v3.x, w.x, fmaf(v3.y, w.y, fmaf(v3.z, w.z, fmaf(v3.w, w.w, a3))));
            }
            u[(size_t)(r0 + 0) * HF + lane] = a0 * dinv[r0 + 0];
            u[(size_t)(r0 + 1) * HF + lane] = a1 * dinv[r0 + 1];
            u[(size_t)(r0 + 2) * HF + lane] = a2 * dinv[r0 + 2];
            u[(size_t)(r0 + 3) * HF + lane] = a3 * dinv[r0 + 3];
        } else {
            for (int i = 0; i < 4; ++i) {
                int r = r0 + i;
                if (r >= n) break;
                const float4* xr = (const float4*)(in + (size_t)r * K);
                float a = 0.f;
                for (int k4 = 0; k4 < K / 4; ++k4) {
                    float4 w = Wl[k4 * HF + lane];
                    float4 v = xr[k4];
                    a = fmaf(v.x, w.x, fmaf(v.y, w.y, fmaf(v.z, w.z, fmaf(v.w, w.w, a))));
                }
                u[(size_t)r * HF + lane] = a * dinv[r];
            }
        }
    }
}

// ---------- aggregation: out[v] = relu(dinv[v]*(sum_in u[s] + u[v]) + b) ----------
__global__ void agg_k(const float* __restrict__ u, const int* __restrict__ col,
                      const int* __restrict__ row_ptr, const int* __restrict__ deg,
                      const float* __restrict__ dinv, const float* __restrict__ bias,
                      float* __restrict__ out, int n) {
    int wave = threadIdx.x >> 6, lane = threadIdx.x & 63;
    int v = blockIdx.x * 4 + wave;
    if (v >= n) return;
    int start = row_ptr[v];
    int end = start + deg[v];
    float acc = u[(size_t)v * HF + lane];  // self loop
    for (int e = start; e < end;) {
        int m = min(64, end - e);
        int c = (lane < m) ? col[e + lane] : 0;
        int t = 0;
        for (; t + 4 <= m; t += 4) {
            int s0 = __shfl(c, t), s1 = __shfl(c, t + 1);
            int s2 = __shfl(c, t + 2), s3 = __shfl(c, t + 3);
            float a0 = u[(size_t)s0 * HF + lane];
            float a1 = u[(size_t)s1 * HF + lane];
            float a2 = u[(size_t)s2 * HF + lane];
            float a3 = u[(size_t)s3 * HF + lane];
            acc += a0; acc += a1; acc += a2; acc += a3;
        }
        for (; t < m; ++t) {
            int s = __shfl(c, t);
            acc += u[(size_t)s * HF + lane];
        }
        e += m;
    }
    out[(size_t)v * HF + lane] = fmaxf(fmaf(acc, dinv[v], bias[lane]), 0.f);
}

// ---------- fused mean-pool + linear head ----------
__device__ __forceinline__ int lower_bound_i(const int* a, int n, int key) {
    int lo = 0, hi = n;
    while (lo < hi) { int mid = (lo + hi) >> 1; if (a[mid] < key) lo = mid + 1; else hi = mid; }
    return lo;
}

__global__ void pool_head_k(const float* __restrict__ h, const int* __restrict__ batch,
                            const float* __restrict__ Wl, const float* __restrict__ bl,
                            float* __restrict__ out, int n) {
    __shared__ float ssum[4][HF];
    __shared__ float smean[HF];
    int g = blockIdx.x;
    int wave = threadIdx.x >> 6, lane = threadIdx.x & 63;
    int start = lower_bound_i(batch, n, g);
    int end = lower_bound_i(batch, n, g + 1);
    float acc = 0.f;
    for (int v = start + wave; v < end; v += 4) acc += h[(size_t)v * HF + lane];
    ssum[wave][lane] = acc;
    __syncthreads();
    if (wave == 0) {
        float s = ssum[0][lane] + ssum[1][lane] + ssum[2][lane] + ssum[3][lane];
        float cnt = (float)(end - start);
        smean[lane] = s / fmaxf(cnt, 1.f);
    }
    __syncthreads();
    if (threadIdx.x < 2) {
        float o = bl[threadIdx.x];
        for (int j = 0; j < HF; ++j) o += smean[j] * Wl[j * 2 + threadIdx.x];
        out[g * 2 + threadIdx.x] = o;
    }
}

extern "C" void kernel_launch(void* const* d_in, const int* in_sizes, int n_in,
                              void* d_out, int out_size, void* d_ws, size_t ws_size,
                              hipStream_t stream) {
    const float* x     = (const float*)d_in[0];
    const int*   ei    = (const int*)d_in[1];
    const int*   batch = (const int*)d_in[2];
    const float* W1 = (const float*)d_in[3];
    const float* b1 = (const float*)d_in[4];
    const float* W2 = (const float*)d_in[5];
    const float* b2 = (const float*)d_in[6];
    const float* W3 = (const float*)d_in[7];
    const float* b3 = (const float*)d_in[8];
    const float* Wl = (const float*)d_in[9];
    const float* bl = (const float*)d_in[10];
    float* outp = (float*)d_out;

    const int N = N_NODES;
    const int E = in_sizes[1] / 2;
    const int NB = (N + BNODES - 1) >> BSHIFT;        // 196 buckets
    const int NBLK = (E + ECHUNK - 1) / ECHUNK;       // edge chunks
    const int M = NB * NBLK;                          // (bucket, chunk) counts

    char* ws = (char*)d_ws;
    size_t off = 0;
    auto alloc = [&](size_t bytes) {
        void* p = ws + off;
        off = (off + bytes + 255) & ~size_t(255);
        return p;
    };
    float*  P    = (float*)alloc((size_t)N * HF * 4);
    float*  U    = (float*)alloc((size_t)N * HF * 4);   // also holds sorted edges (int2, E*8 == N*HF*4)
    int*    colA = (int*)alloc((size_t)E * 4);
    int*    deg  = (int*)alloc((size_t)N * 4);
    float*  dinv = (float*)alloc((size_t)N * 4);
    int*    rowp = (int*)alloc((size_t)N * 4);
    int*    cnt  = (int*)alloc((size_t)M * 4);
    int*    scn  = (int*)alloc((size_t)M * 4);
    int*    sums = (int*)alloc(1024);
    float4* W4_1 = (float4*)alloc((size_t)(128 / 4) * HF * 16);
    float4* W4_2 = (float4*)alloc((size_t)(64 / 4) * HF * 16);
    float4* W4_3 = (float4*)alloc((size_t)(64 / 4) * HF * 16);
    int2*   es   = (int2*)U;
    (void)ws_size; (void)n_in; (void)out_size;

    const int* src = ei;
    const int* dst = ei + E;

    // ---- build bucket-sorted edge list + CSR (no memsets needed) ----
    bhist_k<<<NBLK, 256, 0, stream>>>(dst, cnt, E, NBLK, NB);
    int nb = (M + SCAN_CHUNK - 1) / SCAN_CHUNK;
    scan1_k<<<nb, SCAN_T, 0, stream>>>(cnt, scn, sums, M);
    scan2_k<<<1, SCAN_T, 0, stream>>>(sums, nb);
    scan3_k<<<(M + 255) / 256, 256, 0, stream>>>(scn, sums, M);
    scatter_k<<<NBLK, 256, 0, stream>>>(src, dst, scn, es, E, NBLK, NB);
    fill2_k<<<NB, 256, 0, stream>>>(es, scn, rowp, deg, dinv, colA, E, NBLK, NB, N);

    // one-time W transforms (cheap)
    wtrans_k<<<(32 * HF + 255) / 256, 256, 0, stream>>>(W1, W4_1, 32 * HF);
    wtrans_k<<<(16 * HF + 255) / 256, 256, 0, stream>>>(W2, W4_2, 16 * HF);
    wtrans_k<<<(16 * HF + 255) / 256, 256, 0, stream>>>(W3, W4_3, 16 * HF);

    int gRow = (N + 3) / 4;       // agg: 4 nodes/block
    int gRow64 = (N + 63) / 64;   // gemm: 64 rows/block
    // layer 1 (K=128)
    gemm2_k<128><<<gRow64, 256, 0, stream>>>(x, W4_1, dinv, U, N);
    agg_k<<<gRow, 256, 0, stream>>>(U, colA, rowp, deg, dinv, b1, P, N);
    // layer 2 (K=64)
    gemm2_k<64><<<gRow64, 256, 0, stream>>>(P, W4_2, dinv, U, N);
    agg_k<<<gRow, 256, 0, stream>>>(U, colA, rowp, deg, dinv, b2, P, N);
    // layer 3 (K=64)
    gemm2_k<64><<<gRow64, 256, 0, stream>>>(P, W4_3, dinv, U, N);
    agg_k<<<gRow, 256, 0, stream>>>(U, colA, rowp, deg, dinv, b3, P, N);

    pool_head_k<<<N_GRAPHS, 256, 0, stream>>>(P, batch, Wl, bl, outp, N);
}